// Round 3
// baseline (235.910 us; speedup 1.0000x reference)
//
#include <hip/hip_runtime.h>
#include <math.h>

typedef float f32x4 __attribute__((ext_vector_type(4)));
typedef __bf16 bf16x8 __attribute__((ext_vector_type(8)));

__device__ __forceinline__ unsigned short f2bf(float f) {
  unsigned u = __float_as_uint(f);
  unsigned r = (u + 0x7fffu + ((u >> 16) & 1u)) >> 16;
  return (unsigned short)r;
}
__device__ __forceinline__ float bf2f(unsigned short h) {
  return __uint_as_float(((unsigned)h) << 16);
}

// ---------------- fp32 -> bf16 conversion (x) ----------------
__global__ __launch_bounds__(256) void k_cvt(const float* __restrict__ in,
                                             unsigned short* __restrict__ out, int n4) {
  int i = blockIdx.x * 256 + threadIdx.x;
  if (i < n4) {
    float4 v = ((const float4*)in)[i];
    ushort4 o;
    o.x = f2bf(v.x); o.y = f2bf(v.y); o.z = f2bf(v.z); o.w = f2bf(v.w);
    ((ushort4*)out)[i] = o;
  }
}

// ---------------- softmax over freq_w[513] ----------------
__global__ __launch_bounds__(256) void k_softmax(const float* __restrict__ fw,
                                                 float* __restrict__ wspec) {
  __shared__ float red[4];
  int tid = threadIdx.x;
  float m = -1e30f;
  for (int i = tid; i < 513; i += 256) m = fmaxf(m, fw[i]);
  #pragma unroll
  for (int o = 32; o; o >>= 1) m = fmaxf(m, __shfl_down(m, o));
  if ((tid & 63) == 0) red[tid >> 6] = m;
  __syncthreads();
  m = fmaxf(fmaxf(red[0], red[1]), fmaxf(red[2], red[3]));
  float s = 0.f;
  for (int i = tid; i < 513; i += 256) s += expf(fw[i] - m);
  #pragma unroll
  for (int o = 32; o; o >>= 1) s += __shfl_down(s, o);
  __syncthreads();
  if ((tid & 63) == 0) red[tid >> 6] = s;
  __syncthreads();
  s = red[0] + red[1] + red[2] + red[3];
  float inv = 1.f / s;
  for (int i = tid; i < 513; i += 256) wspec[i] = expf(fw[i] - m) * inv;
}

// ---------------- s = irfft(wspec), length 1024 (exact integer angle reduction) ----------------
__global__ __launch_bounds__(256) void k_s(const float* __restrict__ wspec,
                                           float* __restrict__ s) {
  int gid = blockIdx.x * 256 + threadIdx.x;   // 8192 threads
  int d = gid >> 3;
  int chunk = gid & 7;
  float acc = 0.f;
  for (int f = 1 + chunk; f < 512; f += 8) {
    int p = (f * d) & 1023;
    acc += wspec[f] * __cosf(6.283185307179586f * (float)p * (1.f / 1024.f));
  }
  acc += __shfl_xor(acc, 1);
  acc += __shfl_xor(acc, 2);
  acc += __shfl_xor(acc, 4);
  if (chunk == 0) {
    float w0 = wspec[0], w512 = wspec[512];
    float tot = w0 + ((d & 1) ? -w512 : w512) + 2.f * acc;
    s[d] = tot * (1.f / 1024.f);
  }
}

// ---------------- weights prep: cvt proj_w, cvt down_w, fill circulant Sb ----------------
__global__ __launch_bounds__(256) void k_weights(const float* __restrict__ pw,
                                                 const float* __restrict__ dw,
                                                 const float* __restrict__ s,
                                                 unsigned short* __restrict__ pwb,
                                                 unsigned short* __restrict__ dwb,
                                                 unsigned short* __restrict__ Sb) {
  int b = blockIdx.x;
  int tid = threadIdx.x;
  if (b < 1024) {
    int i = b * 256 + tid;
    float4 v = ((const float4*)pw)[i];
    ushort4 o;
    o.x = f2bf(v.x); o.y = f2bf(v.y); o.z = f2bf(v.z); o.w = f2bf(v.w);
    ((ushort4*)pwb)[i] = o;
  } else if (b < 2048) {
    int i = (b - 1024) * 256 + tid;
    float4 v = ((const float4*)dw)[i];
    ushort4 o;
    o.x = f2bf(v.x); o.y = f2bf(v.y); o.z = f2bf(v.z); o.w = f2bf(v.w);
    ((ushort4*)dwb)[i] = o;
  } else {
    int idx = (b - 2048) * 256 + tid;     // 262144 ushort4's
    int n = idx >> 8;
    int k0 = (idx & 255) * 4;
    ushort4 o;
    o.x = f2bf(s[(k0 + 0 - n) & 1023]);
    o.y = f2bf(s[(k0 + 1 - n) & 1023]);
    o.z = f2bf(s[(k0 + 2 - n) & 1023]);
    o.w = f2bf(s[(k0 + 3 - n) & 1023]);
    ((ushort4*)Sb)[idx] = o;
  }
}

// ---------------- block reduction helper ----------------
__device__ __forceinline__ float blk_sum(float v, float* red, int tid) {
  #pragma unroll
  for (int o = 32; o; o >>= 1) v += __shfl_down(v, o);
  __syncthreads();
  if ((tid & 63) == 0) red[tid >> 6] = v;
  __syncthreads();
  return red[0] + red[1] + red[2] + red[3];
}

// ---------------- per-row LayerNorm in place (bf16 -> bf16) + zero U2 ----------------
__global__ __launch_bounds__(256) void k_ln(unsigned short* __restrict__ comp,
                                            const float* __restrict__ ln_g,
                                            const float* __restrict__ ln_b,
                                            float* __restrict__ u2) {
  __shared__ float red[4];
  const int tid = threadIdx.x;
  const size_t rowoff = (size_t)blockIdx.x * 1024;
  if (tid == 0) u2[blockIdx.x] = 0.f;
  ushort4 cv = ((const ushort4*)(comp + rowoff))[tid];
  float x0 = bf2f(cv.x), x1 = bf2f(cv.y), x2 = bf2f(cv.z), x3 = bf2f(cv.w);
  float mu = blk_sum(x0 + x1 + x2 + x3, red, tid) * (1.f / 1024.f);
  float d0 = x0 - mu, d1 = x1 - mu, d2 = x2 - mu, d3 = x3 - mu;
  float var = blk_sum(d0 * d0 + d1 * d1 + d2 * d2 + d3 * d3, red, tid) * (1.f / 1024.f);
  float inv = rsqrtf(var + 1e-5f);
  float4 g = ((const float4*)ln_g)[tid];
  float4 b = ((const float4*)ln_b)[tid];
  ushort4 o;
  o.x = f2bf(d0 * inv * g.x + b.x);
  o.y = f2bf(d1 * inv * g.y + b.y);
  o.z = f2bf(d2 * inv * g.z + b.z);
  o.w = f2bf(d3 * inv * g.w + b.w);
  ((ushort4*)(comp + rowoff))[tid] = o;
}

__device__ __forceinline__ float gamma_from_u2(float U2, float tv) {
  const float sc = 0.01f;      // sqrt(1e-4)
  const float c = 1e-4f;
  float nrm = sqrtf(U2);
  float nu = fmaxf(nrm, 1e-7f);
  float su = fminf(fmaxf(sc * nu, 1e-7f), 1.f - 1e-5f);
  float Af = tanhf((1.f - tv) * atanhf(su)) / (sc * nu);
  float nvn = fmaxf(fabsf(tv) * nrm, 1e-7f);
  float svv = fminf(fmaxf(sc * nvn, 1e-7f), 1.f - 1e-5f);
  float Bf = tv * tanhf(tv * atanhf(svv)) / (sc * nvn);
  float x2s = Af * Af * U2, y2s = Bf * Bf * U2, xys = Af * Bf * U2;
  float numc = (1.f + 2.f * c * xys + c * y2s) * Af + (1.f - c * x2s) * Bf;
  float den = fmaxf(1.f + 2.f * c * xys + c * c * x2s * y2s, 1e-7f);
  return numc / den;
}

// ---------------- bf16 MFMA GEMM: C[m,n] = sum_k A[m,k]*B[n,k], K=1024 ----------------
// grid: (M/128) m-tiles x 8 n-tiles (bm = bid>>3, bn = bid&7). C row stride 1024.
// MODE 0: silu -> bf16.   MODE 1: plain -> bf16.
// MODE 2: gam(u2[row])*scale -> fp32 (gam computed in-kernel into LDS).
// MODE 3: no C store; atomicAdd per-row sum of C^2 into u2.
template <int MODE>
__global__ __launch_bounds__(256) void k_gemm(const unsigned short* __restrict__ A,
                                              const unsigned short* __restrict__ B,
                                              void* __restrict__ Cout,
                                              const float* __restrict__ scale_ptr,
                                              const float* __restrict__ t_ptr,
                                              float* __restrict__ u2) {
  __shared__ __align__(16) unsigned short As[128 * 64];
  __shared__ __align__(16) unsigned short Bs[128 * 64];
  __shared__ float gsh[128];
  const int tid = threadIdx.x;
  const int lane = tid & 63;
  const int wave = tid >> 6;
  const int bm = (blockIdx.x >> 3) * 128;
  const int bn = (blockIdx.x & 7) * 128;
  const int mhalf = (wave & 1) * 64;
  const int nhalf = (wave >> 1) * 64;
  f32x4 acc[4][4] = {};

  if (MODE == 2) {
    if (tid < 128) {
      float U2v = u2[bm + tid];
      gsh[tid] = gamma_from_u2(U2v, t_ptr[0]) * scale_ptr[0];
    }
  }

  const int ar = tid >> 3;        // row within a 32-row staging round
  const int ac = (tid & 7) * 8;   // bf16 element offset within row
  const unsigned short* Abase = A + (size_t)(bm + ar) * 1024 + ac;
  const unsigned short* Bbase = B + (size_t)(bn + ar) * 1024 + ac;
  char* AsB = (char*)As;
  char* BsB = (char*)Bs;

  for (int kt = 0; kt < 16; ++kt) {
    const int k0 = kt * 64;
    #pragma unroll
    for (int r = 0; r < 4; ++r) {
      __builtin_amdgcn_global_load_lds(
          (const __attribute__((address_space(1))) void*)(Abase + (size_t)(r * 32) * 1024 + k0),
          (__attribute__((address_space(3))) void*)(AsB + r * 4096 + wave * 1024), 16, 0, 0);
      __builtin_amdgcn_global_load_lds(
          (const __attribute__((address_space(1))) void*)(Bbase + (size_t)(r * 32) * 1024 + k0),
          (__attribute__((address_space(3))) void*)(BsB + r * 4096 + wave * 1024), 16, 0, 0);
    }
    __syncthreads();
    const int mrow = lane & 15;
    const int kq = lane >> 4;
    #pragma unroll
    for (int kc = 0; kc < 2; ++kc) {
      bf16x8 af[4], bfr[4];
      #pragma unroll
      for (int mt = 0; mt < 4; ++mt)
        af[mt] = *(const bf16x8*)(AsB + (mhalf + mt * 16 + mrow) * 128 + kc * 64 + kq * 16);
      #pragma unroll
      for (int nt = 0; nt < 4; ++nt)
        bfr[nt] = *(const bf16x8*)(BsB + (nhalf + nt * 16 + mrow) * 128 + kc * 64 + kq * 16);
      #pragma unroll
      for (int mt = 0; mt < 4; ++mt)
        #pragma unroll
        for (int nt = 0; nt < 4; ++nt)
          acc[mt][nt] = __builtin_amdgcn_mfma_f32_16x16x32_bf16(af[mt], bfr[nt], acc[mt][nt], 0, 0, 0);
    }
    __syncthreads();
  }

  const int col = bn + nhalf + (lane & 15);
  const int lrow = mhalf + (lane >> 4) * 4;   // row within block tile
  #pragma unroll
  for (int mt = 0; mt < 4; ++mt)
    #pragma unroll
    for (int r = 0; r < 4; ++r) {
      const int row = bm + lrow + mt * 16 + r;
      if (MODE == 3) {
        float v0 = acc[mt][0][r], v1 = acc[mt][1][r], v2 = acc[mt][2][r], v3 = acc[mt][3][r];
        float ssq = v0 * v0 + v1 * v1 + v2 * v2 + v3 * v3;
        ssq += __shfl_xor(ssq, 1);
        ssq += __shfl_xor(ssq, 2);
        ssq += __shfl_xor(ssq, 4);
        ssq += __shfl_xor(ssq, 8);
        if ((lane & 15) == 0) atomicAdd(&u2[row], ssq);
      } else {
        float rowscl = (MODE == 2) ? gsh[lrow + mt * 16 + r] : 0.f;
        #pragma unroll
        for (int nt = 0; nt < 4; ++nt) {
          float v = acc[mt][nt][r];
          size_t idx = (size_t)row * 1024 + (col + nt * 16);
          if (MODE == 0) {
            float sv = v / (1.f + expf(-v));
            ((unsigned short*)Cout)[idx] = f2bf(sv);
          } else if (MODE == 1) {
            ((unsigned short*)Cout)[idx] = f2bf(v);
          } else {
            ((float*)Cout)[idx] = v * rowscl;
          }
        }
      }
    }
}

extern "C" void kernel_launch(void* const* d_in, const int* in_sizes, int n_in,
                              void* d_out, int out_size, void* d_ws, size_t ws_size,
                              hipStream_t stream) {
  const float* x      = (const float*)d_in[0];
  const float* proj_w = (const float*)d_in[1];
  const float* ln_g   = (const float*)d_in[2];
  const float* ln_b   = (const float*)d_in[3];
  const float* freq_w = (const float*)d_in[4];
  const float* t_p    = (const float*)d_in[5];
  const float* down_w = (const float*)d_in[6];
  const float* scale  = (const float*)d_in[7];

  char* ws = (char*)d_ws;                                   // ws_size = 256 MiB
  unsigned short* xb   = (unsigned short*)ws;               // 16 MB
  unsigned short* pwb  = (unsigned short*)(ws + (16u << 20)); // 2 MB
  unsigned short* dwb  = (unsigned short*)(ws + (18u << 20)); // 2 MB
  unsigned short* comp = (unsigned short*)(ws + (20u << 20)); // 16 MB
  unsigned short* Sb   = (unsigned short*)(ws + (36u << 20)); // 2 MB
  unsigned short* W2   = (unsigned short*)(ws + (38u << 20)); // 2 MB
  float* wspec         = (float*)(ws + (40u << 20));          // 2.05 KB
  float* s_buf         = (float*)(ws + (40u << 20) + 8192);   // 4 KB
  float* u2            = (float*)(ws + (40u << 20) + 16384);  // 32 KB

  k_softmax<<<1, 256, 0, stream>>>(freq_w, wspec);
  k_s<<<32, 256, 0, stream>>>(wspec, s_buf);
  k_cvt<<<8192, 256, 0, stream>>>(x, xb, 2097152);
  k_weights<<<3072, 256, 0, stream>>>(proj_w, down_w, s_buf, pwb, dwb, Sb);
  k_gemm<0><<<512, 256, 0, stream>>>(xb, pwb, (void*)comp, nullptr, nullptr, nullptr);
  k_ln<<<8192, 256, 0, stream>>>(comp, ln_g, ln_b, u2);
  k_gemm<3><<<512, 256, 0, stream>>>(comp, Sb, nullptr, nullptr, nullptr, u2);
  k_gemm<1><<<64, 256, 0, stream>>>(dwb, Sb, (void*)W2, nullptr, nullptr, nullptr);
  k_gemm<2><<<512, 256, 0, stream>>>(comp, W2, d_out, scale, t_p, u2);
}